// Round 26
// baseline (66.720 us; speedup 1.0000x reference)
//
#include <hip/hip_runtime.h>
#include <hip/hip_fp16.h>
#include <stdint.h>

#define NB 4
#define SS 192
#define NI 256

typedef __attribute__((ext_vector_type(8))) _Float16 f16x8;
typedef __attribute__((ext_vector_type(2))) __fp16 fp16v2;
typedef __attribute__((ext_vector_type(16))) float f32x16;

__device__ __forceinline__ uint16_t f2h(float f) {
  union { _Float16 h; uint16_t u; } t; t.h = (_Float16)f; return t.u;
}

__device__ __forceinline__ uint32_t cvt2(float lo, float hi) {
  union { fp16v2 h; uint32_t u; } t;
  t.h = __builtin_amdgcn_cvt_pkrtz(lo, hi);
  return t.u;
}

__device__ __forceinline__ uint4 pack8h(const float4 a, const float4 b) {
  uint4 r;
  r.x = cvt2(a.x, a.y);
  r.y = cvt2(a.z, a.w);
  r.z = cvt2(b.x, b.y);
  r.w = cvt2(b.z, b.w);
  return r;
}

__device__ __forceinline__ uint32_t hmul2(uint32_t x, uint32_t y) {
  union { uint32_t u; __half2 h; } a, b, c;
  a.u = x; b.u = y;
  c.h = __hmul2(a.h, b.h);
  return c.u;
}

// Canonical fp16 storage: row-major, 8-elem chunk c stored at position c ^ (row&15).
// s_hdT is s_hd TRANSPOSED: [d][h].
// partial[] contract (THIS ROUND): 1024 chunks of 16384 floats;
//   w_red[i] = sum(partial[4i..4i+3])   (i-row of W = 65536 floats = 4 chunks).

// ---------------- K_A: fused-score blocks (0..11) + HH/HS converts (12..59) + W partials (60..1083) ----------------
__global__ __launch_bounds__(512) void kA(
    const float* __restrict__ W,
    const float* __restrict__ h_head, const float* __restrict__ h_dep, const float* __restrict__ h_sib,
    const float* __restrict__ U, const float* __restrict__ V, const float* __restrict__ Z,
    float* __restrict__ partial,
    uint16_t* __restrict__ HH, uint16_t* __restrict__ HS,
    float* __restrict__ s_hdT, float* __restrict__ s_hs, float* __restrict__ s_ds) {
  const int bi = blockIdx.x, tid = threadIdx.x;

  if (bi >= 60) {
    // ---- W chunk: sum 16384 consecutive floats ----
    __shared__ float red[8];
    const int c = bi - 60;                         // 0..1023
    const float4* pw = (const float4*)(W + (size_t)c * 16384);
    float4 a = {0.f, 0.f, 0.f, 0.f};
    #pragma unroll
    for (int it = 0; it < 8; ++it) {
      const float4 v = pw[it * 512 + tid];
      a.x += v.x; a.y += v.y; a.z += v.z; a.w += v.w;
    }
    float s = (a.x + a.y) + (a.z + a.w);
    for (int off = 32; off > 0; off >>= 1) s += __shfl_down(s, off, 64);
    if ((tid & 63) == 0) red[tid >> 6] = s;
    __syncthreads();
    if (tid == 0) {
      float t = 0.f;
      #pragma unroll
      for (int q = 0; q < 8; ++q) t += red[q];
      partial[c] = t;
    }
    return;
  }
  if (bi >= 12) {
    // ---- converts: canonical swizzled fp16 (HH, HS) for k3 ----
    const int rl = tid >> 5, c8 = tid & 31;
    const int g = (bi - 12) * 16 + rl;             // 0..767
    const int dst = g * 32 + (c8 ^ (g & 15));
    const int srci = g * 64 + c8 * 2;
    { const float4 x = ((const float4*)h_head)[srci], y = ((const float4*)h_head)[srci + 1];
      ((uint4*)HH)[dst] = pack8h(x, y); }
    { const float4 x = ((const float4*)h_sib)[srci], y = ((const float4*)h_sib)[srci + 1];
      ((uint4*)HS)[dst] = pack8h(x, y); }
    return;
  }

  // ================= fused score block =================
  // which: 0 -> s_hdT (stage1: Q=dU=HD x U^T ; stage2 SWAPPED: m=Q rows(d), n=HH strips)
  //        1 -> s_hs  (stage1: Q=T2=HS x V^T ; stage2: m=h_head rows, n=Q)
  //        2 -> s_ds  (stage1: Q=TZ=HS x Z^T ; stage2: m=h_dep rows, n=Q)
  __shared__ __align__(16) unsigned char smem[147456];   // 144 KB
  unsigned char* Ah1 = smem;                 // stage1 A [192x128], 48 KB
  unsigned char* Bh1 = smem + 49152;         // stage1 B [256x128], 64 KB
  unsigned char* Qb  = smem;                 // Q [2 halves][192x128], 96 KB (overlays stage1)
  unsigned char* Ah2 = smem + 98304;         // stage2 A [192x128], 48 KB
  const int which = bi >> 2, b = bi & 3;
  const float* A1 = (which == 0) ? h_dep : h_sib;
  const float* B1 = (which == 0) ? U : (which == 1) ? V : Z;
  const float* A2 = (which == 2) ? h_dep : h_head;
  float* Os = (which == 0) ? s_hdT : (which == 1) ? s_hs : s_ds;
  const int lane = tid & 63, w = tid >> 6;
  const int l31 = lane & 31, l5 = lane >> 5;

  // ---- stage 1: acc1[mt] = A1-rows x (B1-rows strip w*32), K=256 ----
  f32x16 acc1[6] = {};
  #pragma unroll
  for (int kh = 0; kh < 2; ++kh) {
    const int kbase = kh * 128;
    if (kh) __syncthreads();
    #pragma unroll
    for (int i = 0; i < 6; ++i) {                  // Ah1: 3072 slots
      const int slot = i * 512 + tid;
      const int row = slot >> 4, ck = slot & 15;
      const float* sp = A1 + (size_t)(b * SS + row) * NI + kbase + ck * 8;
      const float4 x = *(const float4*)sp, y = *(const float4*)(sp + 4);
      *(uint4*)(Ah1 + row * 256 + ((ck ^ (row & 15)) << 4)) = pack8h(x, y);
    }
    #pragma unroll
    for (int i = 0; i < 8; ++i) {                  // Bh1: 4096 slots (256 B1-rows)
      const int slot = i * 512 + tid;
      const int row = slot >> 4, ck = slot & 15;
      const float* sp = B1 + (size_t)row * NI + kbase + ck * 8;
      const float4 x = *(const float4*)sp, y = *(const float4*)(sp + 4);
      *(uint4*)(Bh1 + row * 256 + ((ck ^ (row & 15)) << 4)) = pack8h(x, y);
    }
    __syncthreads();
    const int brow = w * 32 + l31;
    const int bbyte = brow * 256;
    const int bmask = brow & 15;
    #pragma unroll
    for (int ks = 0; ks < 8; ++ks) {
      const int sl = ks * 2 + l5;
      f16x8 bf = *reinterpret_cast<const f16x8*>(Bh1 + bbyte + ((sl ^ bmask) << 4));
      #pragma unroll
      for (int mt = 0; mt < 6; ++mt) {
        const int ar = mt * 32 + l31;
        f16x8 af = *reinterpret_cast<const f16x8*>(Ah1 + ar * 256 + ((sl ^ (ar & 15)) << 4));
        acc1[mt] = __builtin_amdgcn_mfma_f32_32x32x16_f16(af, bf, acc1[mt], 0, 0, 0);
      }
    }
  }
  __syncthreads();   // stage1 reads done; Q may overwrite Ah1/Bh1

  // ---- write Q[m][i] (fp16, canonical swizzle, i-halves of 128) ----
  {
    const int i = w * 32 + l31;        // 0..255, half = w>>2
    unsigned char* Qh = Qb + (w >> 2) * 49152;
    const int ic = i & 127, ck = ic >> 3, pos = i & 7;
    #pragma unroll
    for (int mt = 0; mt < 6; ++mt) {
      #pragma unroll
      for (int r = 0; r < 16; ++r) {
        const int m = mt * 32 + (r & 3) + 8 * (r >> 2) + 4 * l5;
        *(uint16_t*)(Qh + m * 256 + ((ck ^ (m & 15)) << 4) + pos * 2) = f2h(acc1[mt][r]);
      }
    }
  }
  __syncthreads();

  // ---- stage 2: 6 waves (n-strip w*32), waves 6,7 stage only ----
  f32x16 acc2[6] = {};
  #pragma unroll
  for (int kh = 0; kh < 2; ++kh) {
    const int kbase = kh * 128;
    if (kh) __syncthreads();
    #pragma unroll
    for (int i = 0; i < 6; ++i) {                  // Ah2: 3072 slots
      const int slot = i * 512 + tid;
      const int row = slot >> 4, ck = slot & 15;
      const float* sp = A2 + (size_t)(b * SS + row) * NI + kbase + ck * 8;
      const float4 x = *(const float4*)sp, y = *(const float4*)(sp + 4);
      *(uint4*)(Ah2 + row * 256 + ((ck ^ (row & 15)) << 4)) = pack8h(x, y);
    }
    __syncthreads();
    if (w < 6) {
      const unsigned char* Qh = Qb + kh * 49152;
      const int brow = w * 32 + l31;
      #pragma unroll
      for (int ks = 0; ks < 8; ++ks) {
        const int sl = ks * 2 + l5;
        // which==0: m-side = Q (d rows), n-side = Ah2 (h_head). Others: m = Ah2, n = Q.
        const unsigned char* mTile = (which == 0) ? Qh : Ah2;
        const unsigned char* nTile = (which == 0) ? Ah2 : Qh;
        f16x8 bf = *reinterpret_cast<const f16x8*>(nTile + brow * 256 + ((sl ^ (brow & 15)) << 4));
        #pragma unroll
        for (int mt = 0; mt < 6; ++mt) {
          const int ar = mt * 32 + l31;
          f16x8 af = *reinterpret_cast<const f16x8*>(mTile + ar * 256 + ((sl ^ (ar & 15)) << 4));
          acc2[mt] = __builtin_amdgcn_mfma_f32_32x32x16_f16(af, bf, acc2[mt], 0, 0, 0);
        }
      }
    }
  }
  if (w < 6) {
    const int n = w * 32 + l31;
    #pragma unroll
    for (int mt = 0; mt < 6; ++mt) {
      #pragma unroll
      for (int r = 0; r < 16; ++r) {
        const int m = mt * 32 + (r & 3) + 8 * (r >> 2) + 4 * l5;
        Os[(size_t)(b * SS + m) * SS + n] = acc2[mt][r];
      }
    }
  }
}

// ---------------- K3: main GEMM — R25 geometry (96h x 96s, 9 waves, 3 blk/CU) ----------------
__global__ __launch_bounds__(576) void k3_big(
    const uint16_t* __restrict__ HH, const uint16_t* __restrict__ HS,
    const float* __restrict__ h_dep, const float* __restrict__ partial,
    const float* __restrict__ s_hdT, const float* __restrict__ s_hs,
    const float* __restrict__ s_ds,
    const float* __restrict__ bias, float* __restrict__ out) {
  __shared__ __align__(16) uint16_t Btile[96 * 128];   // 24 KB
  __shared__ __align__(16) uint16_t Atile[96 * 128];   // 24 KB
  __shared__ __align__(16) uint16_t cvec[NI];
  __shared__ float chd_s[96];
  const int d = blockIdx.x, hb = blockIdx.y >> 1, sb = blockIdx.y & 1, b = blockIdx.z;
  const int tid = threadIdx.x;
  const int lane = tid & 63, w = tid >> 6;
  const int wh = w / 3, ws = w % 3;
  const int l31 = lane & 31, l5 = lane >> 5;

  if (tid < NI) {
    // partial[] = 1024 chunks of 16384; i-row tid = chunks 4*tid..4*tid+3
    const float wr = partial[4 * tid] + partial[4 * tid + 1]
                   + partial[4 * tid + 2] + partial[4 * tid + 3];
    cvec[tid] = f2h(wr * h_dep[(size_t)(b * SS + d) * NI + tid]);
  } else if (tid < NI + 96) {
    const int t = tid - NI;
    chd_s[t] = s_hdT[(size_t)(b * SS + d) * SS + hb * 96 + t];
  }
  __syncthreads();

  f32x16 acc = {};

  #pragma unroll
  for (int half = 0; half < 2; ++half) {
    const int kbase = half * 128;
    if (half) __syncthreads();
    #pragma unroll
    for (int i = 0; i < 3; ++i) {
      const int slot = i * 576 + tid;
      if (slot < 1536) {
        const int row = slot >> 4;
        const uint16_t* src = HS + ((size_t)(b * SS + sb * 96 + row) << 8) + kbase + (slot & 15) * 8;
        __builtin_amdgcn_global_load_lds(
            (const __attribute__((address_space(1))) void*)src,
            (__attribute__((address_space(3))) void*)(Btile + (size_t)slot * 8),
            16, 0, 0);
      }
    }
    #pragma unroll
    for (int i = 0; i < 3; ++i) {
      const int slot = i * 576 + tid;
      if (slot < 1536) {
        const int row = slot >> 4;
        const int kc = slot & 15;
        const int lcl = kc ^ (row & 15);
        const uint4 cv4 = *(const uint4*)(cvec + kbase + lcl * 8);
        const uint4 hh4 = *(const uint4*)(HH + ((size_t)(b * SS + hb * 96 + row) << 8) + kbase + kc * 8);
        uint4 a4;
        a4.x = hmul2(hh4.x, cv4.x);
        a4.y = hmul2(hh4.y, cv4.y);
        a4.z = hmul2(hh4.z, cv4.z);
        a4.w = hmul2(hh4.w, cv4.w);
        *(uint4*)((char*)Atile + (size_t)slot * 16) = a4;
      }
    }
    __syncthreads();
    const int arow = wh * 32 + l31;
    const int abyte = arow * 256;
    const int amask = arow & 15;
    const int brow = ws * 32 + l31;
    const int bbyte = brow * 256;
    const int bmask = brow & 15;
    #pragma unroll
    for (int ks = 0; ks < 8; ++ks) {
      const int sl = ks * 2 + l5;
      f16x8 af = *reinterpret_cast<const f16x8*>((const char*)Atile + abyte + ((sl ^ amask) << 4));
      f16x8 bf = *reinterpret_cast<const f16x8*>((const char*)Btile + bbyte + ((sl ^ bmask) << 4));
      acc = __builtin_amdgcn_mfma_f32_32x32x16_f16(af, bf, acc, 0, 0, 0);
    }
  }

  const float bias0 = bias[0];
  const int s = sb * 96 + ws * 32 + l31;
  const float dsv = s_ds[(size_t)(b * SS + d) * SS + s];
  #pragma unroll
  for (int r = 0; r < 16; ++r) {
    const int hl = wh * 32 + (r & 3) + 8 * (r >> 2) + 4 * l5;
    const float v = acc[r] + chd_s[hl] + bias0
                  + s_hs[(size_t)(b * SS + hb * 96 + hl) * SS + s] + dsv;
    out[((size_t)(b * SS + hb * 96 + hl) * SS + d) * SS + s] = v;
  }
}

extern "C" void kernel_launch(void* const* d_in, const int* in_sizes, int n_in,
                              void* d_out, int out_size, void* d_ws, size_t ws_size,
                              hipStream_t stream) {
  const float* h_head = (const float*)d_in[0];
  const float* h_dep  = (const float*)d_in[1];
  const float* h_sib  = (const float*)d_in[2];
  const float* W_tri  = (const float*)d_in[3];
  const float* U_hd   = (const float*)d_in[4];
  const float* V_hs   = (const float*)d_in[5];
  const float* Z_ds   = (const float*)d_in[6];
  const float* bias   = (const float*)d_in[7];
  float* out = (float*)d_out;

  float* ws = (float*)d_ws;
  float* partial = ws;          ws += 1024;
  float* s_hdT   = ws;          ws += NB * SS * SS;
  float* s_hs    = ws;          ws += NB * SS * SS;
  float* s_ds    = ws;          ws += NB * SS * SS;
  uint16_t* HH   = (uint16_t*)ws;
  uint16_t* HS   = HH + NB * SS * NI;

  kA<<<1084, 512, 0, stream>>>(W_tri, h_head, h_dep, h_sib, U_hd, V_hs, Z_ds,
                               partial, HH, HS, s_hdT, s_hs, s_ds);
  k3_big<<<dim3(SS, 4, NB), 576, 0, stream>>>(HH, HS, h_dep, partial,
                                              s_hdT, s_hs, s_ds, bias, out);
}

// Round 27
// 63.975 us; speedup vs baseline: 1.0429x; 1.0429x over previous
//
#include <hip/hip_runtime.h>
#include <hip/hip_fp16.h>
#include <stdint.h>

#define NB 4
#define SS 192
#define NI 256

typedef __attribute__((ext_vector_type(8))) _Float16 f16x8;
typedef __attribute__((ext_vector_type(2))) __fp16 fp16v2;
typedef __attribute__((ext_vector_type(16))) float f32x16;

__device__ __forceinline__ uint16_t f2h(float f) {
  union { _Float16 h; uint16_t u; } t; t.h = (_Float16)f; return t.u;
}

__device__ __forceinline__ uint32_t cvt2(float lo, float hi) {
  union { fp16v2 h; uint32_t u; } t;
  t.h = __builtin_amdgcn_cvt_pkrtz(lo, hi);
  return t.u;
}

__device__ __forceinline__ uint4 pack8h(const float4 a, const float4 b) {
  uint4 r;
  r.x = cvt2(a.x, a.y);
  r.y = cvt2(a.z, a.w);
  r.z = cvt2(b.x, b.y);
  r.w = cvt2(b.z, b.w);
  return r;
}

__device__ __forceinline__ uint32_t hmul2(uint32_t x, uint32_t y) {
  union { uint32_t u; __half2 h; } a, b, c;
  a.u = x; b.u = y;
  c.h = __hmul2(a.h, b.h);
  return c.u;
}

// Canonical fp16 storage: row-major, 8-elem chunk c stored at position c ^ (row&15).
// CV is stored LOGICAL (unswizzled). s_hdT is s_hd transposed: [d][h].
// partial[] contract: 2048 chunks of 8192 floats; w_red[i] = sum(partial[8i..8i+7]).

// ---------------- K_A: s1-blocks (0..23) + HH/HD/HS converts (24..119) + W partials (120..2167) ----------------
__global__ __launch_bounds__(256) void kA(
    const float* __restrict__ W,
    const float* __restrict__ h_head, const float* __restrict__ h_dep, const float* __restrict__ h_sib,
    const float* __restrict__ U, const float* __restrict__ V, const float* __restrict__ Z,
    float* __restrict__ partial,
    uint16_t* __restrict__ HH, uint16_t* __restrict__ HD, uint16_t* __restrict__ HS,
    uint16_t* __restrict__ dU16, uint16_t* __restrict__ T216, uint16_t* __restrict__ TZ16) {
  const int bi = blockIdx.x, tid = threadIdx.x;

  if (bi >= 120) {
    __shared__ float red[4];
    const int c = bi - 120;
    const float4* pw = (const float4*)(W + (size_t)c * 8192);
    float4 a = {0.f, 0.f, 0.f, 0.f};
    #pragma unroll
    for (int it = 0; it < 8; ++it) {
      const float4 v = pw[it * 256 + tid];
      a.x += v.x; a.y += v.y; a.z += v.z; a.w += v.w;
    }
    float s = (a.x + a.y) + (a.z + a.w);
    for (int off = 32; off > 0; off >>= 1) s += __shfl_down(s, off, 64);
    if ((tid & 63) == 0) red[tid >> 6] = s;
    __syncthreads();
    if (tid == 0) partial[c] = red[0] + red[1] + red[2] + red[3];
    return;
  }
  if (bi >= 24) {
    const int rl = tid >> 5, c8 = tid & 31;
    const int g = (bi - 24) * 8 + rl;              // 0..767
    const int dst = g * 32 + (c8 ^ (g & 15));
    const int srci = g * 64 + c8 * 2;
    { const float4 x = ((const float4*)h_head)[srci], y = ((const float4*)h_head)[srci + 1];
      ((uint4*)HH)[dst] = pack8h(x, y); }
    { const float4 x = ((const float4*)h_dep)[srci], y = ((const float4*)h_dep)[srci + 1];
      ((uint4*)HD)[dst] = pack8h(x, y); }
    { const float4 x = ((const float4*)h_sib)[srci], y = ((const float4*)h_sib)[srci + 1];
      ((uint4*)HS)[dst] = pack8h(x, y); }
    return;
  }

  // ---- s1 block: dU/T2/TZ = A(192xK) x B(U/V/Z rows)^T, self-converting staging ----
  {
    __shared__ __align__(16) uint16_t Ah[192 * 128];   // 48 KB
    __shared__ __align__(16) uint16_t Bh[128 * 128];   // 32 KB
    const int which = bi >> 3, rem = bi & 7;
    const int b = rem >> 1, nt = rem & 1;
    const float* As = (which == 0) ? h_dep : h_sib;
    const float* Bs = (which == 0) ? U : (which == 1) ? V : Z;
    uint16_t* Os = (which == 0) ? dU16 : (which == 1) ? T216 : TZ16;
    const int lane = tid & 63, w = tid >> 6;
    const int l31 = lane & 31, l5 = lane >> 5;
    const int N0 = nt * 128;
    f32x16 acc[6] = {};

    #pragma unroll
    for (int kh = 0; kh < 2; ++kh) {
      const int kbase = kh * 128;
      if (kh) __syncthreads();
      #pragma unroll
      for (int i = 0; i < 12; ++i) {
        const int slot = i * 256 + tid;
        const int row = slot >> 4, ck = slot & 15;
        const float* sp = As + (size_t)(b * SS + row) * NI + kbase + ck * 8;
        const float4 x = *(const float4*)sp, y = *(const float4*)(sp + 4);
        *(uint4*)((char*)Ah + row * 256 + ((ck ^ (row & 15)) << 4)) = pack8h(x, y);
      }
      #pragma unroll
      for (int i = 0; i < 8; ++i) {
        const int slot = i * 256 + tid;
        const int row = slot >> 4, ck = slot & 15;
        const float* sp = Bs + (size_t)(N0 + row) * NI + kbase + ck * 8;
        const float4 x = *(const float4*)sp, y = *(const float4*)(sp + 4);
        *(uint4*)((char*)Bh + row * 256 + ((ck ^ (row & 15)) << 4)) = pack8h(x, y);
      }
      __syncthreads();
      const int brow = w * 32 + l31;
      const int bbyte = brow * 256;
      const int bmask = brow & 15;
      #pragma unroll
      for (int ks = 0; ks < 8; ++ks) {
        const int sl = ks * 2 + l5;
        f16x8 bf = *reinterpret_cast<const f16x8*>((const char*)Bh + bbyte + ((sl ^ bmask) << 4));
        #pragma unroll
        for (int mt = 0; mt < 6; ++mt) {
          const int ar = mt * 32 + l31;
          f16x8 af = *reinterpret_cast<const f16x8*>((const char*)Ah + ar * 256 + ((sl ^ (ar & 15)) << 4));
          acc[mt] = __builtin_amdgcn_mfma_f32_32x32x16_f16(af, bf, acc[mt], 0, 0, 0);
        }
      }
    }
    const int n = N0 + w * 32 + l31;
    const int nck = n >> 3, npos = n & 7;
    #pragma unroll
    for (int mt = 0; mt < 6; ++mt) {
      #pragma unroll
      for (int r = 0; r < 16; ++r) {
        const int m = mt * 32 + (r & 3) + 8 * (r >> 2) + 4 * l5;
        Os[(size_t)(b * SS + m) * NI + ((nck ^ (m & 15)) << 3) + npos] = f2h(acc[mt][r]);
      }
    }
  }
}

// ---------------- K2: s_hdT (which=0, swapped operands) / s_hs / s_ds + CV precompute (which=3) ----------------
__global__ __launch_bounds__(384, 1) void k_s2(
    const uint16_t* __restrict__ HH, const uint16_t* __restrict__ HD,
    const uint16_t* __restrict__ dU16, const uint16_t* __restrict__ T216, const uint16_t* __restrict__ TZ16,
    const float* __restrict__ h_dep, const float* __restrict__ partial,
    float* __restrict__ s_hdT, float* __restrict__ s_hs, float* __restrict__ s_ds,
    uint16_t* __restrict__ CV) {
  __shared__ __align__(16) uint16_t Ah[192 * 128];   // 48 KB
  __shared__ __align__(16) uint16_t Bh[192 * 128];   // 48 KB
  const int which = blockIdx.x, b = blockIdx.y;
  const int tid = threadIdx.x, lane = tid & 63, w = tid >> 6;
  const int l31 = lane & 31, l5 = lane >> 5;

  if (which == 3) {
    __shared__ float wred[NI];
    if (tid < NI) {
      float wr = 0.f;
      #pragma unroll
      for (int q = 0; q < 8; ++q) wr += partial[8 * tid + q];
      wred[tid] = wr;
    }
    __syncthreads();
    #pragma unroll
    for (int i = 0; i < 16; ++i) {
      const int slot = i * 384 + tid;              // 6144 slots = 192 rows x 32 chunks
      const int d = slot >> 5, c8 = slot & 31;
      const float* sp = h_dep + (size_t)(b * SS + d) * NI + c8 * 8;
      float4 x = *(const float4*)sp, y = *(const float4*)(sp + 4);
      const float* wp = wred + c8 * 8;
      x.x *= wp[0]; x.y *= wp[1]; x.z *= wp[2]; x.w *= wp[3];
      y.x *= wp[4]; y.y *= wp[5]; y.z *= wp[6]; y.w *= wp[7];
      ((uint4*)CV)[(size_t)(b * SS + d) * 32 + c8] = pack8h(x, y);
    }
    return;
  }

  const uint16_t* As = (which == 0) ? dU16 : (which == 2) ? HD : HH;
  const uint16_t* Bs = (which == 0) ? HH : (which == 1) ? T216 : TZ16;
  float* Os = (which == 0) ? s_hdT : (which == 1) ? s_hs : s_ds;
  f32x16 acc[6] = {};

  #pragma unroll
  for (int kh = 0; kh < 2; ++kh) {
    const int kbase = kh * 128;
    if (kh) __syncthreads();
    #pragma unroll
    for (int i = 0; i < 8; ++i) {
      const int slot = i * 384 + tid;
      const int row = slot >> 4, ck = slot & 15;
      const uint16_t* src = As + (size_t)(b * SS + row) * NI + kbase + ck * 8;
      __builtin_amdgcn_global_load_lds((const __attribute__((address_space(1))) void*)src,
          (__attribute__((address_space(3))) void*)(Ah + (size_t)slot * 8), 16, 0, 0);
    }
    #pragma unroll
    for (int i = 0; i < 8; ++i) {
      const int slot = i * 384 + tid;
      const int row = slot >> 4, ck = slot & 15;
      const uint16_t* src = Bs + (size_t)(b * SS + row) * NI + kbase + ck * 8;
      __builtin_amdgcn_global_load_lds((const __attribute__((address_space(1))) void*)src,
          (__attribute__((address_space(3))) void*)(Bh + (size_t)slot * 8), 16, 0, 0);
    }
    __syncthreads();
    const int brow = w * 32 + l31;
    const int bbyte = brow * 256;
    const int bmask = brow & 15;
    #pragma unroll
    for (int ks = 0; ks < 8; ++ks) {
      const int sl = ks * 2 + l5;
      f16x8 bf = *reinterpret_cast<const f16x8*>((const char*)Bh + bbyte + ((sl ^ bmask) << 4));
      #pragma unroll
      for (int mt = 0; mt < 6; ++mt) {
        const int ar = mt * 32 + l31;
        f16x8 af = *reinterpret_cast<const f16x8*>((const char*)Ah + ar * 256 + ((sl ^ (ar & 15)) << 4));
        acc[mt] = __builtin_amdgcn_mfma_f32_32x32x16_f16(af, bf, acc[mt], 0, 0, 0);
      }
    }
  }
  const int n = w * 32 + l31;
  #pragma unroll
  for (int mt = 0; mt < 6; ++mt) {
    #pragma unroll
    for (int r = 0; r < 16; ++r) {
      const int m = mt * 32 + (r & 3) + 8 * (r >> 2) + 4 * l5;
      Os[(size_t)(b * SS + m) * SS + n] = acc[mt][r];
    }
  }
}

// ---------------- K3: main GEMM — R21 geometry (96h x 96s, 9 waves, 3 blk/CU), contiguous prologue ----------------
__global__ __launch_bounds__(576) void k3_big(
    const uint16_t* __restrict__ HH, const uint16_t* __restrict__ HS,
    const uint16_t* __restrict__ CV, const float* __restrict__ s_hdT,
    const float* __restrict__ s_hs, const float* __restrict__ s_ds,
    const float* __restrict__ bias, float* __restrict__ out) {
  __shared__ __align__(16) uint16_t Btile[96 * 128];   // 24 KB
  __shared__ __align__(16) uint16_t Atile[96 * 128];   // 24 KB
  __shared__ __align__(16) uint16_t cvec[NI];
  __shared__ float chd_s[96];
  const int d = blockIdx.x, hb = blockIdx.y >> 1, sb = blockIdx.y & 1, b = blockIdx.z;
  const int tid = threadIdx.x;
  const int lane = tid & 63, w = tid >> 6;
  const int wh = w / 3, ws = w % 3;
  const int l31 = lane & 31, l5 = lane >> 5;

  // prologue: ALL contiguous — 32 uint4 (cvec) + 96 floats (chd row from s_hdT)
  if (tid < 32) {
    ((uint4*)cvec)[tid] = ((const uint4*)(CV + (size_t)(b * SS + d) * NI))[tid];
  } else if (tid >= 64 && tid < 160) {
    const int t = tid - 64;
    chd_s[t] = s_hdT[(size_t)(b * SS + d) * SS + hb * 96 + t];
  }
  __syncthreads();

  f32x16 acc = {};

  #pragma unroll
  for (int half = 0; half < 2; ++half) {
    const int kbase = half * 128;
    if (half) __syncthreads();
    #pragma unroll
    for (int i = 0; i < 3; ++i) {
      const int slot = i * 576 + tid;
      if (slot < 1536) {
        const int row = slot >> 4;
        const uint16_t* src = HS + ((size_t)(b * SS + sb * 96 + row) << 8) + kbase + (slot & 15) * 8;
        __builtin_amdgcn_global_load_lds(
            (const __attribute__((address_space(1))) void*)src,
            (__attribute__((address_space(3))) void*)(Btile + (size_t)slot * 8),
            16, 0, 0);
      }
    }
    #pragma unroll
    for (int i = 0; i < 3; ++i) {
      const int slot = i * 576 + tid;
      if (slot < 1536) {
        const int row = slot >> 4;
        const int kc = slot & 15;
        const int lcl = kc ^ (row & 15);
        const uint4 cv4 = *(const uint4*)(cvec + kbase + lcl * 8);
        const uint4 hh4 = *(const uint4*)(HH + ((size_t)(b * SS + hb * 96 + row) << 8) + kbase + kc * 8);
        uint4 a4;
        a4.x = hmul2(hh4.x, cv4.x);
        a4.y = hmul2(hh4.y, cv4.y);
        a4.z = hmul2(hh4.z, cv4.z);
        a4.w = hmul2(hh4.w, cv4.w);
        *(uint4*)((char*)Atile + (size_t)slot * 16) = a4;
      }
    }
    __syncthreads();
    const int arow = wh * 32 + l31;
    const int abyte = arow * 256;
    const int amask = arow & 15;
    const int brow = ws * 32 + l31;
    const int bbyte = brow * 256;
    const int bmask = brow & 15;
    #pragma unroll
    for (int ks = 0; ks < 8; ++ks) {
      const int sl = ks * 2 + l5;
      f16x8 af = *reinterpret_cast<const f16x8*>((const char*)Atile + abyte + ((sl ^ amask) << 4));
      f16x8 bf = *reinterpret_cast<const f16x8*>((const char*)Btile + bbyte + ((sl ^ bmask) << 4));
      acc = __builtin_amdgcn_mfma_f32_32x32x16_f16(af, bf, acc, 0, 0, 0);
    }
  }

  const float bias0 = bias[0];
  const int s = sb * 96 + ws * 32 + l31;
  const float dsv = s_ds[(size_t)(b * SS + d) * SS + s];
  #pragma unroll
  for (int r = 0; r < 16; ++r) {
    const int hl = wh * 32 + (r & 3) + 8 * (r >> 2) + 4 * l5;
    const float v = acc[r] + chd_s[hl] + bias0
                  + s_hs[(size_t)(b * SS + hb * 96 + hl) * SS + s] + dsv;
    out[((size_t)(b * SS + hb * 96 + hl) * SS + d) * SS + s] = v;
  }
}

extern "C" void kernel_launch(void* const* d_in, const int* in_sizes, int n_in,
                              void* d_out, int out_size, void* d_ws, size_t ws_size,
                              hipStream_t stream) {
  const float* h_head = (const float*)d_in[0];
  const float* h_dep  = (const float*)d_in[1];
  const float* h_sib  = (const float*)d_in[2];
  const float* W_tri  = (const float*)d_in[3];
  const float* U_hd   = (const float*)d_in[4];
  const float* V_hs   = (const float*)d_in[5];
  const float* Z_ds   = (const float*)d_in[6];
  const float* bias   = (const float*)d_in[7];
  float* out = (float*)d_out;

  float* ws = (float*)d_ws;
  float* partial = ws;          ws += 2048;
  float* s_hdT   = ws;          ws += NB * SS * SS;
  float* s_hs    = ws;          ws += NB * SS * SS;
  float* s_ds    = ws;          ws += NB * SS * SS;
  uint16_t* HH   = (uint16_t*)ws;
  uint16_t* HD   = HH + NB * SS * NI;
  uint16_t* HS   = HD + NB * SS * NI;
  uint16_t* dU16 = HS + NB * SS * NI;
  uint16_t* T216 = dU16 + NB * SS * NI;
  uint16_t* TZ16 = T216 + NB * SS * NI;
  uint16_t* CV   = TZ16 + NB * SS * NI;

  kA<<<2168, 256, 0, stream>>>(W_tri, h_head, h_dep, h_sib, U_hd, V_hs, Z_ds,
                               partial, HH, HD, HS, dU16, T216, TZ16);
  k_s2<<<dim3(4, NB), 384, 0, stream>>>(HH, HD, dU16, T216, TZ16, h_dep, partial,
                                        s_hdT, s_hs, s_ds, CV);
  k3_big<<<dim3(SS, 4, NB), 576, 0, stream>>>(HH, HS, CV, s_hdT,
                                              s_hs, s_ds, bias, out);
}